// Round 1
// baseline (4043.166 us; speedup 1.0000x reference)
//
#include <hip/hip_runtime.h>
#include <stdint.h>
#include <stddef.h>

#define TT 40
#define BB 128
#define HD 512
#define PRE_W 1536
#define XW 1024
#define VOC 10000
#define VPAD 10112
#define MROWS (TT*BB)

typedef __attribute__((ext_vector_type(8))) short short8;
typedef __attribute__((ext_vector_type(4))) float f32x4;

// ---------------- numeric helpers ----------------
__device__ __forceinline__ unsigned short f2bf(float x){
  unsigned u = __builtin_bit_cast(unsigned, x);
  return (unsigned short)((u + 0x7fffu + ((u >> 16) & 1u)) >> 16);
}
__device__ __forceinline__ float bf2f(unsigned short s){
  unsigned u = ((unsigned)s) << 16;
  return __builtin_bit_cast(float, u);
}
__device__ __forceinline__ void split2(float x, unsigned short* hi, unsigned short* lo){
  unsigned short h = f2bf(x);
  *hi = h;
  *lo = f2bf(x - bf2f(h));
}
__device__ __forceinline__ float sigf(float x){ return 1.f / (1.f + __expf(-x)); }

__device__ __forceinline__ f32x4 mfma3(short8 ah, short8 al, short8 bh, short8 bl, f32x4 c){
  c = __builtin_amdgcn_mfma_f32_16x16x32_bf16(ah, bh, c, 0, 0, 0);
  c = __builtin_amdgcn_mfma_f32_16x16x32_bf16(ah, bl, c, 0, 0, 0);
  c = __builtin_amdgcn_mfma_f32_16x16x32_bf16(al, bh, c, 0, 0, 0);
  return c;
}

// ---------------- prep: transpose + split weights ----------------
// src: [K x Nsrc] fp32 (row stride srcStride, starting at srcRow0). dst: [Ndst x K] bf16 hi/lo at row offset n0.
__global__ __launch_bounds__(256) void transpose_split(
    const float* __restrict__ src, int srcStride, int srcRow0,
    int K, int Nsrc, int Ndst,
    unsigned short* __restrict__ dhi, unsigned short* __restrict__ dlo, int n0)
{
  __shared__ float tile[32][33];
  int kb = blockIdx.x * 32, nb = blockIdx.y * 32;
  int tx = threadIdx.x & 31, ty = threadIdx.x >> 5;
#pragma unroll
  for (int i = 0; i < 4; ++i) {
    int k = kb + ty + i * 8, n = nb + tx;
    float v = 0.f;
    if (k < K && n < Nsrc) v = src[(size_t)(srcRow0 + k) * srcStride + n];
    tile[ty + i * 8][tx] = v;
  }
  __syncthreads();
#pragma unroll
  for (int i = 0; i < 4; ++i) {
    int n = nb + ty + i * 8, k = kb + tx;
    if (n < Ndst && k < K) {
      unsigned short hi, lo;
      split2(tile[tx][ty + i * 8], &hi, &lo);
      size_t di = (size_t)(n0 + n) * K + k;
      dhi[di] = hi; dlo[di] = lo;
    }
  }
}

// ---------------- prep: build X = [emb(token) | cnn] split ----------------
__global__ __launch_bounds__(256) void build_x(
    const int* __restrict__ tokens, const float* __restrict__ cnn,
    const float* __restrict__ emb,
    unsigned short* __restrict__ Xhi, unsigned short* __restrict__ Xlo)
{
  size_t idx = (size_t)blockIdx.x * 256 + threadIdx.x;  // over 5120*1024
  int col = (int)(idx & (XW - 1));
  int row = (int)(idx >> 10);           // t*128 + b
  int t = row >> 7, b = row & (BB - 1);
  float v;
  if (col < 512) v = emb[(size_t)tokens[b * TT + t] * 512 + col];
  else           v = cnn[b * 512 + (col - 512)];
  split2(v, &Xhi[idx], &Xlo[idx]);
}

// ---------------- split-bf16 GEMM: C[M,N] = A[M,K] @ B^T[N,K] (+bias) ----------------
// MODE 0: C=pre0 (ldc=1536), 3-section bias. MODE 1: C=logits with row remap b*40+t, col<10000 guard.
template<int MODE>
__global__ __launch_bounds__(256) void gemm_split(
    const unsigned short* __restrict__ Ahi, const unsigned short* __restrict__ Alo,
    const unsigned short* __restrict__ Bhi, const unsigned short* __restrict__ Blo,
    float* __restrict__ C, int K, int Ntiles,
    const float* __restrict__ bias0, const float* __restrict__ bias1,
    const float* __restrict__ bias2)
{
  __shared__ unsigned short Bs[2][128 * 64];   // hi, lo; 16KB each
  int nwg = gridDim.x;
  int bid0 = blockIdx.x;
  int bid = (nwg % 8 == 0) ? (bid0 % 8) * (nwg / 8) + bid0 / 8 : bid0;  // XCD swizzle
  const int mt = bid / Ntiles, nt = bid % Ntiles;
  const int tid = threadIdx.x;
  const int w = tid >> 6, l = tid & 63;
  const int wr = w >> 1, wc = w & 1;           // 2x2 waves, each 64x64
  const int lr = l & 15, lq = l >> 4;
  f32x4 acc[4][4];
#pragma unroll
  for (int m = 0; m < 4; ++m)
#pragma unroll
    for (int n = 0; n < 4; ++n) acc[m][n] = (f32x4)0.f;
  char* bs0 = (char*)&Bs[0][0];
  char* bs1 = (char*)&Bs[1][0];
  for (int kt = 0; kt < K; kt += 64) {
    __syncthreads();
#pragma unroll
    for (int c = tid; c < 1024; c += 256) {    // 128 rows x 8 chunks of 16B
      int r = c >> 3, k8 = c & 7;
      size_t gi = (size_t)(nt * 128 + r) * K + kt + k8 * 8;
      int lb = ((r * 64 + k8 * 8) * 2) ^ ((r & 7) << 4);
      *(short8*)(bs0 + lb) = *(const short8*)(Bhi + gi);
      *(short8*)(bs1 + lb) = *(const short8*)(Blo + gi);
    }
    __syncthreads();
#pragma unroll
    for (int kk = 0; kk < 2; ++kk) {
      int kg = kt + kk * 32 + lq * 8;
      short8 ah[4], al[4];
#pragma unroll
      for (int m = 0; m < 4; ++m) {
        size_t ai = (size_t)(mt * 128 + wr * 64 + m * 16 + lr) * K + kg;
        ah[m] = *(const short8*)(Ahi + ai);
        al[m] = *(const short8*)(Alo + ai);
      }
#pragma unroll
      for (int n = 0; n < 4; ++n) {
        int nl = wc * 64 + n * 16 + lr;
        int lb = ((nl * 64 + kk * 32 + lq * 8) * 2) ^ ((nl & 7) << 4);
        short8 bh = *(const short8*)(bs0 + lb);
        short8 bl = *(const short8*)(bs1 + lb);
#pragma unroll
        for (int m = 0; m < 4; ++m)
          acc[m][n] = mfma3(ah[m], al[m], bh, bl, acc[m][n]);
      }
    }
  }
#pragma unroll
  for (int n = 0; n < 4; ++n) {
    int col = nt * 128 + wc * 64 + n * 16 + lr;
#pragma unroll
    for (int m = 0; m < 4; ++m) {
#pragma unroll
      for (int q = 0; q < 4; ++q) {
        int row = mt * 128 + wr * 64 + m * 16 + lq * 4 + q;
        float v = acc[m][n][q];
        if (MODE == 0) {
          float b = (col < 512) ? bias0[col] : ((col < 1024) ? bias1[col - 512] : bias2[col - 1024]);
          C[(size_t)row * PRE_W + col] = v + b;
        } else {
          if (col < VOC) {
            int t = row >> 7, b2 = row & (BB - 1);
            C[((size_t)b2 * TT + t) * VOC + col] = v + bias0[col];
          }
        }
      }
    }
  }
}

// ---------------- recurrence helpers ----------------
__device__ __forceinline__ void load_w(char* dst, const unsigned short* __restrict__ src, int n0, int K)
{
  int kpc = K >> 3;
  for (int c = threadIdx.x; c < 32 * kpc; c += 256) {
    int r = c / kpc, k8 = c - r * kpc;
    int lb = ((r * K + k8 * 8) * 2) ^ ((r & 7) << 4);
    *(short8*)(dst + lb) = *(const short8*)(src + (size_t)(n0 + r) * K + k8 * 8);
  }
}

// A-frags per-lane direct from global h arrays ([128,512] hi/lo); B from LDS-resident weight slice.
template<int NF>
__device__ __forceinline__ void mm_tile(f32x4* acc,
    const unsigned short* __restrict__ A0h, const unsigned short* __restrict__ A0l,
    const unsigned short* __restrict__ A1h, const unsigned short* __restrict__ A1l,
    int rlane, int klane, const char* ldsW, int loOff, int K, int nlane)
{
  const int nkb = K >> 5;
#pragma unroll 4
  for (int kb = 0; kb < nkb; ++kb) {
    int k = kb * 32 + klane;
    const unsigned short* ph = A0h; const unsigned short* pl = A0l; int kk = k;
    if (A1h != nullptr && k >= 512) { ph = A1h; pl = A1l; kk = k - 512; }
    short8 ah = *(const short8*)(ph + (size_t)rlane * HD + kk);
    short8 al = *(const short8*)(pl + (size_t)rlane * HD + kk);
#pragma unroll
    for (int nf = 0; nf < NF; ++nf) {
      int nl = nlane + nf * 16;
      int off = ((nl * K + k) * 2) ^ ((nl & 7) << 4);
      short8 bh = *(const short8*)(ldsW + off);
      short8 bl = *(const short8*)(ldsW + loOff + off);
      acc[nf] = mfma3(ah, al, bh, bl, acc[nf]);
    }
  }
}

// two-level device barrier; bar[0..7]=sub counters, bar[8]=root, bar[9]=epoch (all zeroed per launch)
__device__ __forceinline__ void gbar(unsigned* bar, int& ep)
{
  __syncthreads();                 // drains each wave's vmem before s_barrier
  ep += 1;
  if (threadIdx.x == 0) {
    __threadfence();               // agent-scope release: push dirty L2 to coherence point
    const int e = ep;
    unsigned o = __hip_atomic_fetch_add(&bar[blockIdx.x >> 5], 1u, __ATOMIC_RELAXED, __HIP_MEMORY_SCOPE_AGENT);
    if (o == (unsigned)(32 * e - 1)) {
      unsigned r = __hip_atomic_fetch_add(&bar[8], 1u, __ATOMIC_RELAXED, __HIP_MEMORY_SCOPE_AGENT);
      if (r == (unsigned)(8 * e - 1))
        __hip_atomic_store(&bar[9], (unsigned)e, __ATOMIC_RELEASE, __HIP_MEMORY_SCOPE_AGENT);
    }
    while (__hip_atomic_load(&bar[9], __ATOMIC_RELAXED, __HIP_MEMORY_SCOPE_AGENT) < (unsigned)e)
      __builtin_amdgcn_s_sleep(2);
  }
  __syncthreads();
  __threadfence();                 // agent-scope acquire: invalidate L1/L2 before reading fresh h
}

// ---------------- fused 2-layer GRU recurrence (persistent, 256 WGs) ----------------
// roles: g<64 UR0(M64xN32)+phaseB C0/C1(M64xN32); 64<=g<192 UR1(M32xN32,K1024); g>=192 PC1(M32xN32)
__global__ __launch_bounds__(256, 1) void recurrence(
    const unsigned short* __restrict__ Wur0h, const unsigned short* __restrict__ Wur0l,
    const unsigned short* __restrict__ Wur1h, const unsigned short* __restrict__ Wur1l,
    const unsigned short* __restrict__ Wc0hh, const unsigned short* __restrict__ Wc0hl,
    const unsigned short* __restrict__ Wc1hh, const unsigned short* __restrict__ Wc1hl,
    const unsigned short* __restrict__ Wcxh, const unsigned short* __restrict__ Wcxl,
    const float* __restrict__ pre0,
    const float* __restrict__ bu1, const float* __restrict__ br1, const float* __restrict__ bc1,
    float* h0f, float* h1f,
    unsigned short* h0h, unsigned short* h0l,
    unsigned short* h1h, unsigned short* h1l,
    float* z0, float* z1, float* pc1,
    unsigned short* rh0h, unsigned short* rh0l,
    unsigned short* rh1h, unsigned short* rh1l,
    unsigned short* h1ah, unsigned short* h1al,
    unsigned* bar, float* outTail)
{
  extern __shared__ char lds[];
  const int g = blockIdx.x, tid = threadIdx.x;
  const int w = tid >> 6, l = tid & 63;
  const int lr = l & 15, lq = l >> 4;

  // one-time LDS weight residency
  if (g < 64) {
    load_w(lds,         Wur0h, (g >> 1) * 32, 512);
    load_w(lds + 32768, Wur0l, (g >> 1) * 32, 512);
    int gb = g & 31;
    const unsigned short* sh = (g < 32) ? Wc0hh : Wc1hh;
    const unsigned short* sl = (g < 32) ? Wc0hl : Wc1hl;
    load_w(lds + 65536,         sh, (gb >> 1) * 32, 512);
    load_w(lds + 65536 + 32768, sl, (gb >> 1) * 32, 512);
  } else if (g < 192) {
    int nt = (g - 64) >> 2;
    load_w(lds,         Wur1h, nt * 32, 1024);
    load_w(lds + 65536, Wur1l, nt * 32, 1024);
  } else {
    int nt = (g - 192) >> 2;
    load_w(lds,         Wcxh, nt * 32, 512);
    load_w(lds + 32768, Wcxl, nt * 32, 512);
  }
  __syncthreads();

  int ep = 0;
  for (int it = 0; it <= TT; ++it) {
    // ---------- phase A: UR0(t=it) || UR1,PC1(t1=it-1) ----------
    if (g < 64) {
      if (it < TT) {
        const int row0 = (g & 1) * 64 + w * 16;
        const int cb = (g >> 1) * 32;
        f32x4 acc[2]; acc[0] = (f32x4)0.f; acc[1] = (f32x4)0.f;
        mm_tile<2>(acc, h0h, h0l, nullptr, nullptr, row0 + lr, lq * 8, lds, 32768, 512, lr);
#pragma unroll
        for (int nf = 0; nf < 2; ++nf) {
          const int col = cb + nf * 16 + lr;
#pragma unroll
          for (int q = 0; q < 4; ++q) {
            const int row = row0 + lq * 4 + q;
            float v = acc[nf][q] + pre0[(size_t)(it * BB + row) * PRE_W + col];
            if (col < HD) {
              z0[row * HD + col] = sigf(v);
            } else {
              int c2 = col - HD;
              float rr = sigf(v);
              float pd = rr * h0f[row * HD + c2];
              split2(pd, &rh0h[row * HD + c2], &rh0l[row * HD + c2]);
            }
          }
        }
      }
    } else if (g < 192) {
      if (it >= 1) {
        const int u = g - 64;
        const int row0 = (u & 3) * 32 + (w & 1) * 16;
        const int col = (u >> 2) * 32 + (w >> 1) * 16 + lr;
        f32x4 acc[1]; acc[0] = (f32x4)0.f;
        mm_tile<1>(acc, h1h, h1l, h0h, h0l, row0 + lr, lq * 8, lds, 65536, 1024, (w >> 1) * 16 + lr);
#pragma unroll
        for (int q = 0; q < 4; ++q) {
          const int row = row0 + lq * 4 + q;
          float v = acc[0][q];
          if (col < HD) {
            z1[row * HD + col] = sigf(v + bu1[col]);
          } else {
            int c2 = col - HD;
            float rr = sigf(v + br1[c2]);
            float pd = rr * h1f[row * HD + c2];
            split2(pd, &rh1h[row * HD + c2], &rh1l[row * HD + c2]);
          }
        }
      }
    } else {
      if (it >= 1) {
        const int u = g - 192;
        const int row0 = (u & 3) * 32 + (w & 1) * 16;
        const int col = (u >> 2) * 32 + (w >> 1) * 16 + lr;
        f32x4 acc[1]; acc[0] = (f32x4)0.f;
        mm_tile<1>(acc, h0h, h0l, nullptr, nullptr, row0 + lr, lq * 8, lds, 32768, 512, (w >> 1) * 16 + lr);
#pragma unroll
        for (int q = 0; q < 4; ++q) {
          const int row = row0 + lq * 4 + q;
          pc1[row * HD + col] = acc[0][q] + bc1[col];
        }
      }
    }
    gbar(bar, ep);
    // ---------- phase B: C0 -> h0 update || C1 -> h1 update ----------
    if (g < 32) {
      if (it < TT) {
        const int row0 = (g & 1) * 64 + w * 16;
        const int cb = (g >> 1) * 32;
        f32x4 acc[2]; acc[0] = (f32x4)0.f; acc[1] = (f32x4)0.f;
        mm_tile<2>(acc, rh0h, rh0l, nullptr, nullptr, row0 + lr, lq * 8, lds + 65536, 32768, 512, lr);
#pragma unroll
        for (int nf = 0; nf < 2; ++nf) {
          const int col = cb + nf * 16 + lr;
#pragma unroll
          for (int q = 0; q < 4; ++q) {
            const int row = row0 + lq * 4 + q;
            float hh = tanhf(acc[nf][q] + pre0[(size_t)(it * BB + row) * PRE_W + 1024 + col]);
            float zz = z0[row * HD + col];
            float hv = h0f[row * HD + col];
            float hn = zz * hv + (1.f - zz) * hh;
            h0f[row * HD + col] = hn;
            split2(hn, &h0h[row * HD + col], &h0l[row * HD + col]);
          }
        }
      }
    } else if (g < 64) {
      if (it >= 1) {
        const int gb = g - 32;
        const int row0 = (gb & 1) * 64 + w * 16;
        const int cb = (gb >> 1) * 32;
        f32x4 acc[2]; acc[0] = (f32x4)0.f; acc[1] = (f32x4)0.f;
        mm_tile<2>(acc, rh1h, rh1l, nullptr, nullptr, row0 + lr, lq * 8, lds + 65536, 32768, 512, lr);
#pragma unroll
        for (int nf = 0; nf < 2; ++nf) {
          const int col = cb + nf * 16 + lr;
#pragma unroll
          for (int q = 0; q < 4; ++q) {
            const int row = row0 + lq * 4 + q;
            float hh = tanhf(acc[nf][q] + pc1[row * HD + col]);
            float zz = z1[row * HD + col];
            float hv = h1f[row * HD + col];
            float hn = zz * hv + (1.f - zz) * hh;
            h1f[row * HD + col] = hn;
            unsigned short hi, lo;
            split2(hn, &hi, &lo);
            h1h[row * HD + col] = hi; h1l[row * HD + col] = lo;
            size_t ai = ((size_t)(it - 1) * BB + row) * HD + col;
            h1ah[ai] = hi; h1al[ai] = lo;
          }
        }
      }
    }
    gbar(bar, ep);
  }

  // final hidden [2,128,512] -> d_out tail
  if (g < 16) {
    for (int i = g * 256 + tid; i < BB * HD; i += 16 * 256) {
      outTail[i] = h0f[i];
      outTail[BB * HD + i] = h1f[i];
    }
  }
}

// ---------------- host ----------------
extern "C" void kernel_launch(void* const* d_in, const int* in_sizes, int n_in,
                              void* d_out, int out_size, void* d_ws, size_t ws_size,
                              hipStream_t stream)
{
  const int*   tokens = (const int*)  d_in[0];
  const float* cnn    = (const float*)d_in[1];
  const float* emb    = (const float*)d_in[2];
  const float* w_u0   = (const float*)d_in[3];
  const float* b_u0   = (const float*)d_in[4];
  const float* w_r0   = (const float*)d_in[5];
  const float* b_r0   = (const float*)d_in[6];
  const float* w_c0   = (const float*)d_in[7];
  const float* b_c0   = (const float*)d_in[8];
  const float* w_u1   = (const float*)d_in[9];
  const float* b_u1   = (const float*)d_in[10];
  const float* w_r1   = (const float*)d_in[11];
  const float* b_r1   = (const float*)d_in[12];
  const float* w_c1   = (const float*)d_in[13];
  const float* b_c1   = (const float*)d_in[14];
  const float* out_w  = (const float*)d_in[15];
  const float* out_b  = (const float*)d_in[16];
  float* out = (float*)d_out;

  char* p = (char*)d_ws;
  auto alloc = [&](size_t bytes) -> char* {
    char* r = p;
    p += (bytes + 255) & ~(size_t)255;
    return r;
  };
  unsigned short* Wur0h = (unsigned short*)alloc(1024 * 512 * 2);
  unsigned short* Wur0l = (unsigned short*)alloc(1024 * 512 * 2);
  unsigned short* Wur1h = (unsigned short*)alloc(1024 * 1024 * 2);
  unsigned short* Wur1l = (unsigned short*)alloc(1024 * 1024 * 2);
  unsigned short* Wc0hh = (unsigned short*)alloc(512 * 512 * 2);
  unsigned short* Wc0hl = (unsigned short*)alloc(512 * 512 * 2);
  unsigned short* Wc1hh = (unsigned short*)alloc(512 * 512 * 2);
  unsigned short* Wc1hl = (unsigned short*)alloc(512 * 512 * 2);
  unsigned short* Wcxh  = (unsigned short*)alloc(512 * 512 * 2);
  unsigned short* Wcxl  = (unsigned short*)alloc(512 * 512 * 2);
  unsigned short* Wx0h  = (unsigned short*)alloc((size_t)1536 * 1024 * 2);
  unsigned short* Wx0l  = (unsigned short*)alloc((size_t)1536 * 1024 * 2);
  unsigned short* Wouth = (unsigned short*)alloc((size_t)VPAD * 512 * 2);
  unsigned short* Woutl = (unsigned short*)alloc((size_t)VPAD * 512 * 2);
  unsigned short* Xhi   = (unsigned short*)alloc((size_t)MROWS * XW * 2);
  unsigned short* Xlo   = (unsigned short*)alloc((size_t)MROWS * XW * 2);
  float*          pre0  = (float*)alloc((size_t)MROWS * PRE_W * 4);
  unsigned short* h1ah  = (unsigned short*)alloc((size_t)MROWS * HD * 2);
  unsigned short* h1al  = (unsigned short*)alloc((size_t)MROWS * HD * 2);
  float*          z0    = (float*)alloc(BB * HD * 4);
  float*          z1    = (float*)alloc(BB * HD * 4);
  float*          pc1   = (float*)alloc(BB * HD * 4);
  unsigned short* rh0h  = (unsigned short*)alloc(BB * HD * 2);
  unsigned short* rh0l  = (unsigned short*)alloc(BB * HD * 2);
  unsigned short* rh1h  = (unsigned short*)alloc(BB * HD * 2);
  unsigned short* rh1l  = (unsigned short*)alloc(BB * HD * 2);
  // zero block (single memset): h0f,h1f,h0h,h0l,h1h,h1l,bar
  char* zbase = p;
  float*          h0f = (float*)alloc(BB * HD * 4);
  float*          h1f = (float*)alloc(BB * HD * 4);
  unsigned short* h0h = (unsigned short*)alloc(BB * HD * 2);
  unsigned short* h0l = (unsigned short*)alloc(BB * HD * 2);
  unsigned short* h1h = (unsigned short*)alloc(BB * HD * 2);
  unsigned short* h1l = (unsigned short*)alloc(BB * HD * 2);
  unsigned*       bar = (unsigned*)alloc(256);
  size_t zbytes = (size_t)(p - zbase);
  hipMemsetAsync(zbase, 0, zbytes, stream);

  dim3 blk(256);
  build_x<<<20480, blk, 0, stream>>>(tokens, cnn, emb, Xhi, Xlo);

  transpose_split<<<dim3(16, 16),  blk, 0, stream>>>(w_u0, 512, 0,   512,  512,   512,   Wur0h, Wur0l, 0);
  transpose_split<<<dim3(16, 16),  blk, 0, stream>>>(w_r0, 512, 0,   512,  512,   512,   Wur0h, Wur0l, 512);
  transpose_split<<<dim3(32, 16),  blk, 0, stream>>>(w_u1, 512, 0,   1024, 512,   512,   Wur1h, Wur1l, 0);
  transpose_split<<<dim3(32, 16),  blk, 0, stream>>>(w_r1, 512, 0,   1024, 512,   512,   Wur1h, Wur1l, 512);
  transpose_split<<<dim3(16, 16),  blk, 0, stream>>>(w_c0, 512, 0,   512,  512,   512,   Wc0hh, Wc0hl, 0);
  transpose_split<<<dim3(16, 16),  blk, 0, stream>>>(w_c1, 512, 0,   512,  512,   512,   Wc1hh, Wc1hl, 0);
  transpose_split<<<dim3(16, 16),  blk, 0, stream>>>(w_c1, 512, 512, 512,  512,   512,   Wcxh,  Wcxl,  0);
  transpose_split<<<dim3(32, 16),  blk, 0, stream>>>(w_u0, 512, 512, 1024, 512,   512,   Wx0h,  Wx0l,  0);
  transpose_split<<<dim3(32, 16),  blk, 0, stream>>>(w_r0, 512, 512, 1024, 512,   512,   Wx0h,  Wx0l,  512);
  transpose_split<<<dim3(32, 16),  blk, 0, stream>>>(w_c0, 512, 512, 1024, 512,   512,   Wx0h,  Wx0l,  1024);
  transpose_split<<<dim3(16, 316), blk, 0, stream>>>(out_w, VOC, 0,  512,  VOC,   VPAD,  Wouth, Woutl, 0);

  gemm_split<0><<<480, blk, 0, stream>>>(Xhi, Xlo, Wx0h, Wx0l, pre0, 1024, 12, b_u0, b_r0, b_c0);

  hipFuncSetAttribute((const void*)recurrence, hipFuncAttributeMaxDynamicSharedMemorySize, 131072);
  recurrence<<<256, blk, 131072, stream>>>(Wur0h, Wur0l, Wur1h, Wur1l, Wc0hh, Wc0hl,
      Wc1hh, Wc1hl, Wcxh, Wcxl, pre0, b_u1, b_r1, b_c1,
      h0f, h1f, h0h, h0l, h1h, h1l, z0, z1, pc1,
      rh0h, rh0l, rh1h, rh1l, h1ah, h1al, bar, out + (size_t)MROWS * VOC);

  gemm_split<1><<<3160, blk, 0, stream>>>(h1ah, h1al, Wouth, Woutl, out, 512, 79, out_b, nullptr, nullptr);
}

// Round 2
// 1616.681 us; speedup vs baseline: 2.5009x; 2.5009x over previous
//
#include <hip/hip_runtime.h>
#include <stdint.h>
#include <stddef.h>

#define TT 40
#define BB 128
#define HD 512
#define NN (BB*HD)
#define PRE_W 1536
#define XW 1024
#define VOC 10000
#define VPAD 10112
#define MROWS (TT*BB)

typedef __attribute__((ext_vector_type(8))) short short8;
typedef __attribute__((ext_vector_type(4))) float f32x4;
typedef __attribute__((ext_vector_type(4))) unsigned uint4v;
typedef __attribute__((ext_vector_type(4))) float float4v;

// ---------------- numeric helpers ----------------
__device__ __forceinline__ unsigned short f2bf(float x){
  unsigned u = __builtin_bit_cast(unsigned, x);
  return (unsigned short)((u + 0x7fffu + ((u >> 16) & 1u)) >> 16);
}
__device__ __forceinline__ float bf2f(unsigned short s){
  unsigned u = ((unsigned)s) << 16;
  return __builtin_bit_cast(float, u);
}
__device__ __forceinline__ void split2(float x, unsigned short* hi, unsigned short* lo){
  unsigned short h = f2bf(x);
  *hi = h;
  *lo = f2bf(x - bf2f(h));
}
__device__ __forceinline__ unsigned packbf(float x){
  unsigned short hi, lo;
  split2(x, &hi, &lo);
  return (unsigned)hi | ((unsigned)lo << 16);
}
__device__ __forceinline__ float sigf(float x){ return 1.f / (1.f + __expf(-x)); }

__device__ __forceinline__ f32x4 mfma3(short8 ah, short8 al, short8 bh, short8 bl, f32x4 c){
  c = __builtin_amdgcn_mfma_f32_16x16x32_bf16(ah, bh, c, 0, 0, 0);
  c = __builtin_amdgcn_mfma_f32_16x16x32_bf16(ah, bl, c, 0, 0, 0);
  c = __builtin_amdgcn_mfma_f32_16x16x32_bf16(al, bh, c, 0, 0, 0);
  return c;
}

// coherent (L3 / device-scope) scalar access — compiles to sc0 sc1 load/store
__device__ __forceinline__ void st_coh(float* p, float v){
  __hip_atomic_store(p, v, __ATOMIC_RELAXED, __HIP_MEMORY_SCOPE_AGENT);
}
__device__ __forceinline__ void st_coh(unsigned* p, unsigned v){
  __hip_atomic_store(p, v, __ATOMIC_RELAXED, __HIP_MEMORY_SCOPE_AGENT);
}
__device__ __forceinline__ float ld_coh(const float* p){
  return __hip_atomic_load(p, __ATOMIC_RELAXED, __HIP_MEMORY_SCOPE_AGENT);
}

// unpack 8 packed words (hi|lo<<16) -> hi-plane short8 + lo-plane short8
__device__ __forceinline__ void unpack8(uint4v w0, uint4v w1, short8* ah, short8* al){
  uint4v hh, ll;
#pragma unroll
  for (int j = 0; j < 4; ++j) {
    unsigned e0 = (j < 2) ? w0[2*j]     : w1[2*(j-2)];
    unsigned e1 = (j < 2) ? w0[2*j + 1] : w1[2*(j-2) + 1];
    hh[j] = __builtin_amdgcn_perm(e1, e0, 0x05040100u);
    ll[j] = __builtin_amdgcn_perm(e1, e0, 0x07060302u);
  }
  *ah = __builtin_bit_cast(short8, hh);
  *al = __builtin_bit_cast(short8, ll);
}

// ---------------- prep: all weight transposes in ONE kernel ----------------
__global__ __launch_bounds__(256) void transpose_all(
    const float* __restrict__ w_u0, const float* __restrict__ w_r0, const float* __restrict__ w_c0,
    const float* __restrict__ w_u1, const float* __restrict__ w_r1, const float* __restrict__ w_c1,
    const float* __restrict__ out_w,
    unsigned short* __restrict__ Wur0h, unsigned short* __restrict__ Wur0l,
    unsigned short* __restrict__ Wur1h, unsigned short* __restrict__ Wur1l,
    unsigned short* __restrict__ Wc0hh, unsigned short* __restrict__ Wc0hl,
    unsigned short* __restrict__ Wc1hh, unsigned short* __restrict__ Wc1hl,
    unsigned short* __restrict__ Wcxh,  unsigned short* __restrict__ Wcxl,
    unsigned short* __restrict__ Wx0h,  unsigned short* __restrict__ Wx0l,
    unsigned short* __restrict__ Wouth, unsigned short* __restrict__ Woutl)
{
  int b = blockIdx.x;
  const float* src; int stride, row0, K, Nsrc, Ndst, n0, nkb;
  unsigned short *dhi, *dlo;
  if      (b < 256)  {          src=w_u0; stride=512; row0=0;   K=512;  Nsrc=512; Ndst=512;  dhi=Wur0h; dlo=Wur0l; n0=0;    nkb=16; }
  else if (b < 512)  { b-=256;  src=w_r0; stride=512; row0=0;   K=512;  Nsrc=512; Ndst=512;  dhi=Wur0h; dlo=Wur0l; n0=512;  nkb=16; }
  else if (b < 1024) { b-=512;  src=w_u1; stride=512; row0=0;   K=1024; Nsrc=512; Ndst=512;  dhi=Wur1h; dlo=Wur1l; n0=0;    nkb=32; }
  else if (b < 1536) { b-=1024; src=w_r1; stride=512; row0=0;   K=1024; Nsrc=512; Ndst=512;  dhi=Wur1h; dlo=Wur1l; n0=512;  nkb=32; }
  else if (b < 1792) { b-=1536; src=w_c0; stride=512; row0=0;   K=512;  Nsrc=512; Ndst=512;  dhi=Wc0hh; dlo=Wc0hl; n0=0;    nkb=16; }
  else if (b < 2048) { b-=1792; src=w_c1; stride=512; row0=0;   K=512;  Nsrc=512; Ndst=512;  dhi=Wc1hh; dlo=Wc1hl; n0=0;    nkb=16; }
  else if (b < 2304) { b-=2048; src=w_c1; stride=512; row0=512; K=512;  Nsrc=512; Ndst=512;  dhi=Wcxh;  dlo=Wcxl;  n0=0;    nkb=16; }
  else if (b < 2816) { b-=2304; src=w_u0; stride=512; row0=512; K=1024; Nsrc=512; Ndst=512;  dhi=Wx0h;  dlo=Wx0l;  n0=0;    nkb=32; }
  else if (b < 3328) { b-=2816; src=w_r0; stride=512; row0=512; K=1024; Nsrc=512; Ndst=512;  dhi=Wx0h;  dlo=Wx0l;  n0=512;  nkb=32; }
  else if (b < 3840) { b-=3328; src=w_c0; stride=512; row0=512; K=1024; Nsrc=512; Ndst=512;  dhi=Wx0h;  dlo=Wx0l;  n0=1024; nkb=32; }
  else               { b-=3840; src=out_w;stride=VOC; row0=0;   K=512;  Nsrc=VOC; Ndst=VPAD; dhi=Wouth; dlo=Woutl; n0=0;    nkb=16; }

  __shared__ float tile[32][33];
  int kb = (b % nkb) * 32, nb = (b / nkb) * 32;
  int tx = threadIdx.x & 31, ty = threadIdx.x >> 5;
#pragma unroll
  for (int i = 0; i < 4; ++i) {
    int k = kb + ty + i * 8, n = nb + tx;
    float v = 0.f;
    if (k < K && n < Nsrc) v = src[(size_t)(row0 + k) * stride + n];
    tile[ty + i * 8][tx] = v;
  }
  __syncthreads();
#pragma unroll
  for (int i = 0; i < 4; ++i) {
    int n = nb + ty + i * 8, k = kb + tx;
    if (n < Ndst && k < K) {
      unsigned short hi, lo;
      split2(tile[tx][ty + i * 8], &hi, &lo);
      size_t di = (size_t)(n0 + n) * K + k;
      dhi[di] = hi; dlo[di] = lo;
    }
  }
}

// ---------------- prep: build X = [emb(token) | cnn] split (8-wide) ----------------
__global__ __launch_bounds__(256) void build_x(
    const int* __restrict__ tokens, const float* __restrict__ cnn,
    const float* __restrict__ emb,
    unsigned short* __restrict__ Xhi, unsigned short* __restrict__ Xlo)
{
  int idx = blockIdx.x * 256 + threadIdx.x;     // over 5120*128 groups of 8
  int c8 = (idx & 127) * 8;
  int row = idx >> 7;                           // t*128 + b
  int t = row >> 7, b = row & (BB - 1);
  const float* src = (c8 < 512) ? (emb + (size_t)tokens[b * TT + t] * 512 + c8)
                                : (cnn + (size_t)b * 512 + (c8 - 512));
  float4v a0 = *(const float4v*)src;
  float4v a1 = *(const float4v*)(src + 4);
  short8 vh, vl;
#pragma unroll
  for (int j = 0; j < 8; ++j) {
    unsigned short hi, lo;
    float v = (j < 4) ? a0[j] : a1[j - 4];
    split2(v, &hi, &lo);
    vh[j] = (short)hi; vl[j] = (short)lo;
  }
  size_t o = (size_t)row * XW + c8;
  *(short8*)(Xhi + o) = vh;
  *(short8*)(Xlo + o) = vl;
}

// ---------------- split-bf16 GEMM: C[M,N] = A[M,K] @ B^T[N,K] (+bias) ----------------
template<int MODE>
__global__ __launch_bounds__(256) void gemm_split(
    const unsigned short* __restrict__ Ahi, const unsigned short* __restrict__ Alo,
    const unsigned short* __restrict__ Bhi, const unsigned short* __restrict__ Blo,
    float* __restrict__ C, int K, int Ntiles,
    const float* __restrict__ bias0, const float* __restrict__ bias1,
    const float* __restrict__ bias2)
{
  __shared__ unsigned short Bs[2][128 * 64];
  int nwg = gridDim.x;
  int bid0 = blockIdx.x;
  int bid = (nwg % 8 == 0) ? (bid0 % 8) * (nwg / 8) + bid0 / 8 : bid0;
  const int mt = bid / Ntiles, nt = bid % Ntiles;
  const int tid = threadIdx.x;
  const int w = tid >> 6, l = tid & 63;
  const int wr = w >> 1, wc = w & 1;
  const int lr = l & 15, lq = l >> 4;
  f32x4 acc[4][4];
#pragma unroll
  for (int m = 0; m < 4; ++m)
#pragma unroll
    for (int n = 0; n < 4; ++n) acc[m][n] = (f32x4)0.f;
  char* bs0 = (char*)&Bs[0][0];
  char* bs1 = (char*)&Bs[1][0];
  for (int kt = 0; kt < K; kt += 64) {
    __syncthreads();
#pragma unroll
    for (int c = tid; c < 1024; c += 256) {
      int r = c >> 3, k8 = c & 7;
      size_t gi = (size_t)(nt * 128 + r) * K + kt + k8 * 8;
      int lb = ((r * 64 + k8 * 8) * 2) ^ ((r & 7) << 4);
      *(short8*)(bs0 + lb) = *(const short8*)(Bhi + gi);
      *(short8*)(bs1 + lb) = *(const short8*)(Blo + gi);
    }
    __syncthreads();
#pragma unroll
    for (int kk = 0; kk < 2; ++kk) {
      int kg = kt + kk * 32 + lq * 8;
      short8 ah[4], al[4];
#pragma unroll
      for (int m = 0; m < 4; ++m) {
        size_t ai = (size_t)(mt * 128 + wr * 64 + m * 16 + lr) * K + kg;
        ah[m] = *(const short8*)(Ahi + ai);
        al[m] = *(const short8*)(Alo + ai);
      }
#pragma unroll
      for (int n = 0; n < 4; ++n) {
        int nl = wc * 64 + n * 16 + lr;
        int lb = ((nl * 64 + kk * 32 + lq * 8) * 2) ^ ((nl & 7) << 4);
        short8 bh = *(const short8*)(bs0 + lb);
        short8 bl = *(const short8*)(bs1 + lb);
#pragma unroll
        for (int m = 0; m < 4; ++m)
          acc[m][n] = mfma3(ah[m], al[m], bh, bl, acc[m][n]);
      }
    }
  }
#pragma unroll
  for (int n = 0; n < 4; ++n) {
    int col = nt * 128 + wc * 64 + n * 16 + lr;
#pragma unroll
    for (int m = 0; m < 4; ++m) {
#pragma unroll
      for (int q = 0; q < 4; ++q) {
        int row = mt * 128 + wr * 64 + m * 16 + lq * 4 + q;
        float v = acc[m][n][q];
        if (MODE == 0) {
          float b = (col < 512) ? bias0[col] : ((col < 1024) ? bias1[col - 512] : bias2[col - 1024]);
          C[(size_t)row * PRE_W + col] = v + b;
        } else {
          if (col < VOC) {
            int t = row >> 7, b2 = row & (BB - 1);
            C[((size_t)b2 * TT + t) * VOC + col] = v + bias0[col];
          }
        }
      }
    }
  }
}

// ---------------- recurrence helpers ----------------
__device__ __forceinline__ void load_w(char* dst, const unsigned short* __restrict__ src, int n0, int K)
{
  int kpc = K >> 3;
  for (int c = threadIdx.x; c < 32 * kpc; c += 256) {
    int r = c / kpc, k8 = c - r * kpc;
    int lb = ((r * K + k8 * 8) * 2) ^ ((r & 7) << 4);
    *(short8*)(dst + lb) = *(const short8*)(src + (size_t)(n0 + r) * K + k8 * 8);
  }
}

// A from packed (hi|lo<<16) global arrays via plain dwordx4 on virgin addresses; B from LDS.
template<int NF>
__device__ __forceinline__ void mm_tile(f32x4* acc,
    const unsigned* __restrict__ A0, const unsigned* __restrict__ A1,
    int rlane, int klane, const char* ldsW, int loOff, int K, int nlane)
{
  const int nkb = K >> 5;
#pragma unroll 8
  for (int kb = 0; kb < nkb; ++kb) {
    int k = kb * 32 + klane;
    const unsigned* pp = A0; int kk = k;
    if (A1 != nullptr && k >= 512) { pp = A1; kk = k - 512; }
    uint4v w0 = *(const uint4v*)(pp + (size_t)rlane * HD + kk);
    uint4v w1 = *(const uint4v*)(pp + (size_t)rlane * HD + kk + 4);
    short8 ah, al;
    unpack8(w0, w1, &ah, &al);
#pragma unroll
    for (int nf = 0; nf < NF; ++nf) {
      int nl = nlane + nf * 16;
      int off = ((nl * K + k) * 2) ^ ((nl & 7) << 4);
      short8 bh = *(const short8*)(ldsW + off);
      short8 bl = *(const short8*)(ldsW + loOff + off);
      acc[nf] = mfma3(ah, al, bh, bl, acc[nf]);
    }
  }
}

// fence-free two-level device barrier (all traffic = agent-scope atomics at L3)
__device__ __forceinline__ void gbar(unsigned* bar, int& ep)
{
  asm volatile("s_waitcnt vmcnt(0)" ::: "memory");   // drain sc1 stores -> visible at L3
  __syncthreads();
  ep += 1;
  if (threadIdx.x == 0) {
    const unsigned e = (unsigned)ep;
    unsigned o = __hip_atomic_fetch_add(&bar[(blockIdx.x >> 5) * 32], 1u, __ATOMIC_RELAXED, __HIP_MEMORY_SCOPE_AGENT);
    if (o == 32u * e - 1u) {
      unsigned r = __hip_atomic_fetch_add(&bar[256], 1u, __ATOMIC_RELAXED, __HIP_MEMORY_SCOPE_AGENT);
      if (r == 8u * e - 1u)
        __hip_atomic_store(&bar[288], e, __ATOMIC_RELAXED, __HIP_MEMORY_SCOPE_AGENT);
    }
    while (__hip_atomic_load(&bar[288], __ATOMIC_RELAXED, __HIP_MEMORY_SCOPE_AGENT) < e)
      __builtin_amdgcn_s_sleep(2);
  }
  __syncthreads();
}

// ---------------- fused 2-layer GRU recurrence (persistent, 256 WGs) ----------------
__global__ __launch_bounds__(256, 1) void recurrence(
    const unsigned short* __restrict__ Wur0h, const unsigned short* __restrict__ Wur0l,
    const unsigned short* __restrict__ Wur1h, const unsigned short* __restrict__ Wur1l,
    const unsigned short* __restrict__ Wc0hh, const unsigned short* __restrict__ Wc0hl,
    const unsigned short* __restrict__ Wc1hh, const unsigned short* __restrict__ Wc1hl,
    const unsigned short* __restrict__ Wcxh, const unsigned short* __restrict__ Wcxl,
    const float* __restrict__ pre0,
    const float* __restrict__ bu1, const float* __restrict__ br1, const float* __restrict__ bc1,
    float* h0f, float* h1f,
    unsigned* h0v, unsigned* h1v, unsigned* rh0v, unsigned* rh1v,
    float* z0, float* z1, float* pc1,
    unsigned short* h1ah, unsigned short* h1al,
    unsigned* bar, float* outTail)
{
  extern __shared__ char lds[];
  const int g = blockIdx.x, tid = threadIdx.x;
  const int w = tid >> 6, l = tid & 63;
  const int lr = l & 15, lq = l >> 4;

  // one-time LDS weight residency
  if (g < 64) {
    load_w(lds,         Wur0h, (g >> 1) * 32, 512);
    load_w(lds + 32768, Wur0l, (g >> 1) * 32, 512);
    int gb = g & 31;
    const unsigned short* sh = (g < 32) ? Wc0hh : Wc1hh;
    const unsigned short* sl = (g < 32) ? Wc0hl : Wc1hl;
    load_w(lds + 65536,         sh, (gb >> 1) * 32, 512);
    load_w(lds + 65536 + 32768, sl, (gb >> 1) * 32, 512);
  } else if (g < 192) {
    int nt = (g - 64) >> 2;
    load_w(lds,         Wur1h, nt * 32, 1024);
    load_w(lds + 65536, Wur1l, nt * 32, 1024);
  } else {
    int nt = (g - 192) >> 2;
    load_w(lds,         Wcxh, nt * 32, 512);
    load_w(lds + 32768, Wcxl, nt * 32, 512);
  }
  __syncthreads();

  int ep = 0;
  for (int it = 0; it <= TT; ++it) {
    // ---------- phase A: UR0(t=it) || UR1,PC1(t1=it-1) ----------
    if (g < 64) {
      if (it < TT) {
        const int row0 = (g & 1) * 64 + w * 16;
        const int cb = (g >> 1) * 32;
        float pre[2][4], hv2[2][4];
#pragma unroll
        for (int nf = 0; nf < 2; ++nf) {
          const int col = cb + nf * 16 + lr;
#pragma unroll
          for (int q = 0; q < 4; ++q) {
            const int row = row0 + lq * 4 + q;
            pre[nf][q] = pre0[(size_t)(it * BB + row) * PRE_W + col];
            if (cb >= HD) hv2[nf][q] = ld_coh(&h0f[row * HD + (col - HD)]);
          }
        }
        f32x4 acc[2]; acc[0] = (f32x4)0.f; acc[1] = (f32x4)0.f;
        mm_tile<2>(acc, h0v + (size_t)it * NN, nullptr, row0 + lr, lq * 8, lds, 32768, 512, lr);
#pragma unroll
        for (int nf = 0; nf < 2; ++nf) {
          const int col = cb + nf * 16 + lr;
#pragma unroll
          for (int q = 0; q < 4; ++q) {
            const int row = row0 + lq * 4 + q;
            float v = acc[nf][q] + pre[nf][q];
            if (cb < HD) {
              st_coh(&z0[row * HD + col], sigf(v));
            } else {
              float pd = sigf(v) * hv2[nf][q];
              st_coh(&rh0v[(size_t)it * NN + row * HD + (col - HD)], packbf(pd));
            }
          }
        }
      }
    } else if (g < 192) {
      if (it >= 1) {
        const int u = g - 64;
        const int row0 = (u & 3) * 32 + (w & 1) * 16;
        const int colb = (u >> 2) * 32 + (w >> 1) * 16;
        const int col = colb + lr;
        float hv2[4], bz[1];
        bz[0] = (colb < HD) ? bu1[col] : br1[col - HD];
#pragma unroll
        for (int q = 0; q < 4; ++q) {
          const int row = row0 + lq * 4 + q;
          if (colb >= HD) hv2[q] = ld_coh(&h1f[row * HD + (col - HD)]);
        }
        f32x4 acc[1]; acc[0] = (f32x4)0.f;
        mm_tile<1>(acc, h1v + (size_t)(it - 1) * NN, h0v + (size_t)it * NN,
                   row0 + lr, lq * 8, lds, 65536, 1024, (w >> 1) * 16 + lr);
#pragma unroll
        for (int q = 0; q < 4; ++q) {
          const int row = row0 + lq * 4 + q;
          float v = acc[0][q] + bz[0];
          if (colb < HD) {
            st_coh(&z1[row * HD + col], sigf(v));
          } else {
            float pd = sigf(v) * hv2[q];
            st_coh(&rh1v[(size_t)(it - 1) * NN + row * HD + (col - HD)], packbf(pd));
          }
        }
      }
    } else {
      if (it >= 1) {
        const int u = g - 192;
        const int row0 = (u & 3) * 32 + (w & 1) * 16;
        const int col = (u >> 2) * 32 + (w >> 1) * 16 + lr;
        float bc = bc1[col];
        f32x4 acc[1]; acc[0] = (f32x4)0.f;
        mm_tile<1>(acc, h0v + (size_t)it * NN, nullptr, row0 + lr, lq * 8, lds, 32768, 512, (w >> 1) * 16 + lr);
#pragma unroll
        for (int q = 0; q < 4; ++q) {
          const int row = row0 + lq * 4 + q;
          st_coh(&pc1[row * HD + col], acc[0][q] + bc);
        }
      }
    }
    gbar(bar, ep);
    // ---------- phase B: C0 -> h0 update || C1 -> h1 update ----------
    if (g < 32) {
      if (it < TT) {
        const int row0 = (g & 1) * 64 + w * 16;
        const int cb = (g >> 1) * 32;
        float pre[2][4], zz[2][4], hv[2][4];
#pragma unroll
        for (int nf = 0; nf < 2; ++nf) {
          const int col = cb + nf * 16 + lr;
#pragma unroll
          for (int q = 0; q < 4; ++q) {
            const int row = row0 + lq * 4 + q;
            pre[nf][q] = pre0[(size_t)(it * BB + row) * PRE_W + 1024 + col];
            zz[nf][q] = ld_coh(&z0[row * HD + col]);
            hv[nf][q] = ld_coh(&h0f[row * HD + col]);
          }
        }
        f32x4 acc[2]; acc[0] = (f32x4)0.f; acc[1] = (f32x4)0.f;
        mm_tile<2>(acc, rh0v + (size_t)it * NN, nullptr, row0 + lr, lq * 8, lds + 65536, 32768, 512, lr);
#pragma unroll
        for (int nf = 0; nf < 2; ++nf) {
          const int col = cb + nf * 16 + lr;
#pragma unroll
          for (int q = 0; q < 4; ++q) {
            const int row = row0 + lq * 4 + q;
            float hh = tanhf(acc[nf][q] + pre[nf][q]);
            float hn = zz[nf][q] * hv[nf][q] + (1.f - zz[nf][q]) * hh;
            st_coh(&h0f[row * HD + col], hn);
            st_coh(&h0v[(size_t)(it + 1) * NN + row * HD + col], packbf(hn));
          }
        }
      }
    } else if (g < 64) {
      if (it >= 1) {
        const int gb = g - 32;
        const int row0 = (gb & 1) * 64 + w * 16;
        const int cb = (gb >> 1) * 32;
        float pcv[2][4], zz[2][4], hv[2][4];
#pragma unroll
        for (int nf = 0; nf < 2; ++nf) {
          const int col = cb + nf * 16 + lr;
#pragma unroll
          for (int q = 0; q < 4; ++q) {
            const int row = row0 + lq * 4 + q;
            pcv[nf][q] = ld_coh(&pc1[row * HD + col]);
            zz[nf][q] = ld_coh(&z1[row * HD + col]);
            hv[nf][q] = ld_coh(&h1f[row * HD + col]);
          }
        }
        f32x4 acc[2]; acc[0] = (f32x4)0.f; acc[1] = (f32x4)0.f;
        mm_tile<2>(acc, rh1v + (size_t)(it - 1) * NN, nullptr, row0 + lr, lq * 8, lds + 65536, 32768, 512, lr);
#pragma unroll
        for (int nf = 0; nf < 2; ++nf) {
          const int col = cb + nf * 16 + lr;
#pragma unroll
          for (int q = 0; q < 4; ++q) {
            const int row = row0 + lq * 4 + q;
            float hh = tanhf(acc[nf][q] + pcv[nf][q]);
            float hn = zz[nf][q] * hv[nf][q] + (1.f - zz[nf][q]) * hh;
            st_coh(&h1f[row * HD + col], hn);
            st_coh(&h1v[(size_t)it * NN + row * HD + col], packbf(hn));
            unsigned short hi, lo;
            split2(hn, &hi, &lo);
            size_t ai = (size_t)(it - 1) * NN + row * HD + col;
            h1ah[ai] = hi; h1al[ai] = lo;    // plain: consumed by next kernel
          }
        }
      }
    }
    gbar(bar, ep);
  }

  // final hidden [2,128,512] -> d_out tail
  if (g < 16) {
    for (int i = g * 256 + tid; i < NN; i += 16 * 256) {
      outTail[i] = ld_coh(&h0f[i]);
      outTail[NN + i] = ld_coh(&h1f[i]);
    }
  }
}

// ---------------- host ----------------
extern "C" void kernel_launch(void* const* d_in, const int* in_sizes, int n_in,
                              void* d_out, int out_size, void* d_ws, size_t ws_size,
                              hipStream_t stream)
{
  const int*   tokens = (const int*)  d_in[0];
  const float* cnn    = (const float*)d_in[1];
  const float* emb    = (const float*)d_in[2];
  const float* w_u0   = (const float*)d_in[3];
  const float* b_u0   = (const float*)d_in[4];
  const float* w_r0   = (const float*)d_in[5];
  const float* b_r0   = (const float*)d_in[6];
  const float* w_c0   = (const float*)d_in[7];
  const float* b_c0   = (const float*)d_in[8];
  const float* w_u1   = (const float*)d_in[9];
  const float* b_u1   = (const float*)d_in[10];
  const float* w_r1   = (const float*)d_in[11];
  const float* b_r1   = (const float*)d_in[12];
  const float* w_c1   = (const float*)d_in[13];
  const float* b_c1   = (const float*)d_in[14];
  const float* out_w  = (const float*)d_in[15];
  const float* out_b  = (const float*)d_in[16];
  float* out = (float*)d_out;

  char* p = (char*)d_ws;
  auto alloc = [&](size_t bytes) -> char* {
    char* r = p;
    p += (bytes + 255) & ~(size_t)255;
    return r;
  };
  unsigned short* Wur0h = (unsigned short*)alloc(1024 * 512 * 2);
  unsigned short* Wur0l = (unsigned short*)alloc(1024 * 512 * 2);
  unsigned short* Wur1h = (unsigned short*)alloc(1024 * 1024 * 2);
  unsigned short* Wur1l = (unsigned short*)alloc(1024 * 1024 * 2);
  unsigned short* Wc0hh = (unsigned short*)alloc(512 * 512 * 2);
  unsigned short* Wc0hl = (unsigned short*)alloc(512 * 512 * 2);
  unsigned short* Wc1hh = (unsigned short*)alloc(512 * 512 * 2);
  unsigned short* Wc1hl = (unsigned short*)alloc(512 * 512 * 2);
  unsigned short* Wcxh  = (unsigned short*)alloc(512 * 512 * 2);
  unsigned short* Wcxl  = (unsigned short*)alloc(512 * 512 * 2);
  unsigned short* Wx0h  = (unsigned short*)alloc((size_t)1536 * 1024 * 2);
  unsigned short* Wx0l  = (unsigned short*)alloc((size_t)1536 * 1024 * 2);
  unsigned short* Wouth = (unsigned short*)alloc((size_t)VPAD * 512 * 2);
  unsigned short* Woutl = (unsigned short*)alloc((size_t)VPAD * 512 * 2);
  unsigned short* Xhi   = (unsigned short*)alloc((size_t)MROWS * XW * 2);
  unsigned short* Xlo   = (unsigned short*)alloc((size_t)MROWS * XW * 2);
  float*          pre0  = (float*)alloc((size_t)MROWS * PRE_W * 4);
  unsigned short* h1ah  = (unsigned short*)alloc((size_t)MROWS * HD * 2);
  unsigned short* h1al  = (unsigned short*)alloc((size_t)MROWS * HD * 2);
  unsigned*       h0v   = (unsigned*)alloc((size_t)(TT + 1) * NN * 4);
  unsigned*       h1v   = (unsigned*)alloc((size_t)(TT + 1) * NN * 4);
  unsigned*       rh0v  = (unsigned*)alloc((size_t)TT * NN * 4);
  unsigned*       rh1v  = (unsigned*)alloc((size_t)TT * NN * 4);
  float*          z0    = (float*)alloc(NN * 4);
  float*          z1    = (float*)alloc(NN * 4);
  float*          pc1   = (float*)alloc(NN * 4);
  // zero block: h0f, h1f, bar
  char* zbase = p;
  float*    h0f = (float*)alloc(NN * 4);
  float*    h1f = (float*)alloc(NN * 4);
  unsigned* bar = (unsigned*)alloc(2048);
  size_t zbytes = (size_t)(p - zbase);

  hipMemsetAsync(zbase, 0, zbytes, stream);
  hipMemsetAsync(h0v, 0, NN * 4, stream);   // slot 0 = initial h0
  hipMemsetAsync(h1v, 0, NN * 4, stream);   // slot 0 = initial h1

  dim3 blk(256);
  transpose_all<<<8896, blk, 0, stream>>>(w_u0, w_r0, w_c0, w_u1, w_r1, w_c1, out_w,
      Wur0h, Wur0l, Wur1h, Wur1l, Wc0hh, Wc0hl, Wc1hh, Wc1hl, Wcxh, Wcxl,
      Wx0h, Wx0l, Wouth, Woutl);
  build_x<<<2560, blk, 0, stream>>>(tokens, cnn, emb, Xhi, Xlo);

  gemm_split<0><<<480, blk, 0, stream>>>(Xhi, Xlo, Wx0h, Wx0l, pre0, 1024, 12, b_u0, b_r0, b_c0);

  hipFuncSetAttribute((const void*)recurrence, hipFuncAttributeMaxDynamicSharedMemorySize, 131072);
  recurrence<<<256, blk, 131072, stream>>>(Wur0h, Wur0l, Wur1h, Wur1l, Wc0hh, Wc0hl,
      Wc1hh, Wc1hl, Wcxh, Wcxl, pre0, b_u1, b_r1, b_c1,
      h0f, h1f, h0v, h1v, rh0v, rh1v, z0, z1, pc1,
      h1ah, h1al, bar, out + (size_t)MROWS * VOC);

  gemm_split<1><<<3160, blk, 0, stream>>>(h1ah, h1al, Wouth, Woutl, out, 512, 79, out_b, nullptr, nullptr);
}